// Round 15
// baseline (303.780 us; speedup 1.0000x reference)
//
#include <hip/hip_runtime.h>
#include <hip/hip_cooperative_groups.h>

namespace cg = cooperative_groups;

#define NTASK 24
#define KSEL 1000
#define NIMG 8
#define NEG_INF_D (-1e30)
#define SEG 192
#define SORTN 2048
#define NBLK 240

// ---------- helpers ----------

static __device__ __forceinline__ unsigned fkey(float x) {
    unsigned u = __float_as_uint(x);
    return u ^ ((u >> 31) ? 0xFFFFFFFFu : 0x80000000u);
}

static __device__ __forceinline__ float fkey_inv(unsigned key) {
    unsigned u = (key >> 31) ? (key ^ 0x80000000u) : ~key;
    return __uint_as_float(u);
}

static __device__ __forceinline__ unsigned long long dkey(double d) {
    unsigned long long u = (unsigned long long)__double_as_longlong(d);
    if (u >> 63) u = ~u; else u |= 0x8000000000000000ull;
    return u;
}

static __device__ __forceinline__ int level_hw(int lvl) {
    return lvl == 0 ? 65536 : (lvl == 1 ? 16384 : 4096);
}

// ---------- the whole pipeline as one cooperative kernel ----------

__global__ __launch_bounds__(1024) void k_mega(
    const float* __restrict__ o2, const float* __restrict__ o3, const float* __restrict__ o4,
    const float* __restrict__ g2, const float* __restrict__ g3, const float* __restrict__ g4,
    const float* __restrict__ a2, const float* __restrict__ a3, const float* __restrict__ a4,
    unsigned* __restrict__ hist, int* __restrict__ cntB, unsigned long long* __restrict__ cand,
    unsigned long long* __restrict__ sorted64,
    double* __restrict__ boxes, double* __restrict__ score, int* __restrict__ valid,
    unsigned long long* __restrict__ maskT,
    int* __restrict__ order, double* __restrict__ s2v,
    float* __restrict__ out) {

    cg::grid_group grid = cg::this_grid();
    const int tid = threadIdx.x;
    const int bid = blockIdx.x;

    __shared__ unsigned long long U64[16000];          // 128,000 B phase union
    __shared__ unsigned long long kwsS[16];
    __shared__ int prefK[16], prefN[16];
    __shared__ int prefS[33];
    __shared__ unsigned scntS;
    __shared__ int sBin, totK;

    // ================= P0: zero hist =================
    {
        int g = bid * 1024 + tid;
        if (g < NTASK * 4096) hist[g] = 0u;
    }
    grid.sync();

    // ================= P1: histogram (768 task-slices, grid-strided) =================
    {
        unsigned* h = (unsigned*)U64;                  // 4096 u32
        for (int vs = bid; vs < 768; vs += NBLK) {
            const int task = vs >> 5, sl = vs & 31;
            const int img = task / 3, lvl = task % 3;
            const float* obj = lvl == 0 ? o2 : (lvl == 1 ? o3 : o4);
            const int HW = level_hw(lvl);
            const int total = 3 * HW;
            const float* base = obj + (size_t)img * total;

            for (int t = tid; t < 4096; t += 1024) h[t] = 0u;
            __syncthreads();

            const int per4 = (total / 32) >> 2;
            const int beg4 = sl * per4;
            const float4* b4 = (const float4*)base;
            for (int t = beg4 + tid; t < beg4 + per4; t += 1024) {
                float4 v = b4[t];
                atomicAdd(&h[fkey(v.x) >> 20], 1u);
                atomicAdd(&h[fkey(v.y) >> 20], 1u);
                atomicAdd(&h[fkey(v.z) >> 20], 1u);
                atomicAdd(&h[fkey(v.w) >> 20], 1u);
            }
            __syncthreads();
            unsigned* H = hist + task * 4096;
            for (int t = tid; t < 4096; t += 1024)
                if (h[t]) atomicAdd(&H[t], h[t]);
            __syncthreads();
        }
    }
    grid.sync();

    // ================= P2: compact (threshold inline, 768 slices) =================
    {
        unsigned* h = (unsigned*)U64;                  // U64[0..2047]
        unsigned* part = (unsigned*)(U64 + 2048);      // 256 u32
        unsigned long long* buf = U64 + 2304;          // 256 u64
        for (int vs = bid; vs < 768; vs += NBLK) {
            const int task = vs >> 5, sl = vs & 31;
            const int img = task / 3, lvl = task % 3;
            const float* obj = lvl == 0 ? o2 : (lvl == 1 ? o3 : o4);
            const int HW = level_hw(lvl);
            const int total = 3 * HW;
            const float* base = obj + (size_t)img * total;

            const unsigned* H = hist + task * 4096;
            for (int t = tid; t < 4096; t += 1024) h[t] = H[t];
            if (tid == 0) scntS = 0u;
            __syncthreads();
            if (tid < 256) {
                unsigned sacc = 0;
                for (int q = 0; q < 16; ++q) sacc += h[tid * 16 + q];
                part[tid] = sacc;
            }
            __syncthreads();
            if (tid == 0) {
                unsigned cum = 0;
                int c = 255;
                for (; c >= 0; --c) {
                    if (cum + part[c] >= (unsigned)KSEL) break;
                    cum += part[c];
                }
                if (c < 0) c = 0;
                int bin = 0;
                for (int b = c * 16 + 15; b >= c * 16; --b) {
                    if (cum + h[b] >= (unsigned)KSEL) { bin = b; break; }
                    cum += h[b];
                }
                sBin = bin;
            }
            __syncthreads();
            const unsigned B = (unsigned)sBin;

            const int per4 = (total / 32) >> 2;
            const int beg4 = sl * per4;
            const float4* b4 = (const float4*)base;
            for (int t = beg4 + tid; t < beg4 + per4; t += 1024) {
                float4 v = b4[t];
                const int e0 = t * 4;
#pragma unroll
                for (int q = 0; q < 4; ++q) {
                    float x = q == 0 ? v.x : (q == 1 ? v.y : (q == 2 ? v.z : v.w));
                    unsigned key = fkey(x);
                    if ((key >> 20) >= B) {
                        unsigned s = atomicAdd(&scntS, 1u);
                        if (s < 256u) {
                            int el = e0 + q;
                            int a = el / HW, pos = el - a * HW;
                            int i = pos * 3 + a;
                            buf[s] = ((unsigned long long)key << 32) | (unsigned)(~(unsigned)i);
                        }
                    }
                }
            }
            __syncthreads();
            int n = (int)scntS; if (n > SEG) n = SEG;
            const int seg = task * 32 + sl;
            if (tid == 0) cntB[seg] = n;
            unsigned long long* C = cand + (size_t)seg * SEG;
            for (int t = tid; t < n; t += 1024) C[t] = buf[t];
            __syncthreads();
        }
    }
    grid.sync();

    // ================= P3: gather + bitonic sort (blocks 0..23) =================
    if (bid < NTASK) {
        const int task = bid;
        const int wid = tid >> 6, lane = tid & 63;
        unsigned long long* comp = U64;                // 2048 u64

        if (tid == 0) {
            int p = 0;
            for (int s = 0; s < 32; ++s) { prefS[s] = p; p += cntB[task * 32 + s]; }
            prefS[32] = p;
        }
        for (int t = tid; t < SORTN; t += 1024) comp[t] = 0ull;
        __syncthreads();

        for (int s = wid; s < 32; s += 16) {
            const int b = prefS[s], n = prefS[s + 1] - b;
            const unsigned long long* C = cand + (size_t)(task * 32 + s) * SEG;
            for (int k = lane; k < n; k += 64)
                if (b + k < SORTN) comp[b + k] = C[k];
        }
        __syncthreads();

        for (unsigned k = 2; k <= SORTN; k <<= 1) {
            for (unsigned j = k >> 1; j > 0; j >>= 1) {
                for (unsigned i = tid; i < SORTN; i += 1024) {
                    unsigned ixj = i ^ j;
                    if (ixj > i) {
                        unsigned long long A = comp[i], Bv = comp[ixj];
                        bool desc = ((i & k) == 0);
                        if ((A < Bv) == desc) { comp[i] = Bv; comp[ixj] = A; }
                    }
                }
                __syncthreads();
            }
        }

        for (int t = tid; t < KSEL; t += 1024) sorted64[task * KSEL + t] = comp[t];
    }
    grid.sync();

    // ================= P4: decode (240 blocks x 100 boxes) =================
    if (tid < 100) {
        const int g = bid * 100 + tid;                 // 240*100 = 24000 exactly
        if (g < NTASK * KSEL) {
            const int task = g / KSEL, r = g - task * KSEL;
            const int img = task / 3, lvl = task % 3;
            const float* brg = lvl == 0 ? g2 : (lvl == 1 ? g3 : g4);
            const float* anc = lvl == 0 ? a2 : (lvl == 1 ? a3 : a4);
            const int HW = level_hw(lvl);
            const int N = HW * 3;
            const double XC = 4.135166556742356;       // log(1000/16)

            unsigned long long e = sorted64[task * KSEL + r];
            unsigned key = (unsigned)(e >> 32);
            int i = (int)(~(unsigned)(e & 0xFFFFFFFFull));
            int a = i % 3, pos = i / 3;

            double x = (double)fkey_inv(key);
            double s = 1.0 / (1.0 + exp(-x));

            const float* bb = brg + (size_t)img * 12 * HW + (size_t)(a * 4) * HW + pos;
            double dx = (double)bb[0];
            double dy = (double)bb[(size_t)HW];
            double dw = (double)bb[(size_t)2 * HW];
            double dh = (double)bb[(size_t)3 * HW];

            const float* an = anc + ((size_t)img * N + (size_t)i) * 4;
            double ax1 = an[0], ay1 = an[1], ax2 = an[2], ay2 = an[3];

            double w = ax2 - ax1 + 1.0, h = ay2 - ay1 + 1.0;
            double cx = ax1 + 0.5 * w, cy = ay1 + 0.5 * h;
            if (dw > XC) dw = XC;
            if (dh > XC) dh = XC;
            double pcx = dx * w + cx, pcy = dy * h + cy;
            double pw = exp(dw) * w, ph = exp(dh) * h;
            double x1 = pcx - 0.5 * pw, y1 = pcy - 0.5 * ph;
            double x2 = pcx + 0.5 * pw - 1.0, y2 = pcy + 0.5 * ph - 1.0;
            x1 = fmin(fmax(x1, 0.0), 1023.0);
            y1 = fmin(fmax(y1, 0.0), 1023.0);
            x2 = fmin(fmax(x2, 0.0), 1023.0);
            y2 = fmin(fmax(y2, 0.0), 1023.0);
            double ws_ = x2 - x1 + 1.0, hs_ = y2 - y1 + 1.0;
            double xc = x1 + ws_ / 2.0, yc = y1 + hs_ / 2.0;
            int v = (ws_ >= 0.0) && (hs_ >= 0.0) && (xc < 1024.0) && (yc < 1024.0);

            double* bo = boxes + (size_t)(task * KSEL + r) * 4;
            bo[0] = x1; bo[1] = y1; bo[2] = x2; bo[3] = y2;
            score[task * KSEL + r] = s;
            valid[task * KSEL + r] = v;
        }
    }
    grid.sync();

    // ================= P5: suppression mask (one wave per 64x64 tile) =================
    {
        const int wid = tid >> 6, lane = tid & 63;
        const int tile = bid * 16 + wid;               // 24*136 = 3264 tiles
        if (tile < NTASK * 136) {
            const int task = tile / 136;
            int I = 0, rem = tile - task * 136;
            while (rem >= 16 - I) { rem -= 16 - I; ++I; }
            const int J = I + rem;

            const double* B = boxes + (size_t)task * KSEL * 4;
            const int j = J * 64 + lane;
            const int jc = j < KSEL ? j : KSEL - 1;
            double jx1 = B[jc * 4 + 0], jy1 = B[jc * 4 + 1];
            double jx2 = B[jc * 4 + 2], jy2 = B[jc * 4 + 3];
            double aj = (jx2 - jx1 + 1.0) * (jy2 - jy1 + 1.0);

            unsigned long long* MT = maskT + (size_t)task * 16000 + (size_t)J * KSEL;
            int iend = I * 64 + 64; if (iend > KSEL) iend = KSEL;
            for (int i = I * 64; i < iend; ++i) {
                double ix1 = B[i * 4 + 0], iy1 = B[i * 4 + 1];
                double ix2 = B[i * 4 + 2], iy2 = B[i * 4 + 3];
                double ai = (ix2 - ix1 + 1.0) * (iy2 - iy1 + 1.0);
                double xx1 = fmax(ix1, jx1), yy1 = fmax(iy1, jy1);
                double xx2 = fmin(ix2, jx2), yy2 = fmin(iy2, jy2);
                double iw = xx2 - xx1 + 1.0; iw = iw > 0.0 ? iw : 0.0;
                double ih = yy2 - yy1 + 1.0; ih = ih > 0.0 ? ih : 0.0;
                double inter = iw * ih;
                double iou = inter / (ai + aj - inter);
                bool sup = (j > i) && (j < KSEL) && (iou > 0.7);
                unsigned long long m = __ballot(sup);
                if (lane == 0) MT[i] = m;
            }
        }
    }
    grid.sync();

    // ================= P6: greedy NMS (blocks 0..23) =================
    if (bid < NTASK) {
        const int task = bid;
        const int wid = tid >> 6, lane = tid & 63;
        unsigned long long* Msh = U64;                 // 16000 u64

        {
            const ulonglong2* MG = (const ulonglong2*)(maskT + (size_t)task * 16000);
            ulonglong2* ML = (ulonglong2*)Msh;
            for (int t = tid; t < 8000; t += 1024) ML[t] = MG[t];
        }
        if (tid < 16) kwsS[tid] = 0ull;
        __syncthreads();
        if (tid < KSEL && valid[task * KSEL + tid])
            atomicOr(&kwsS[tid >> 6], 1ull << (tid & 63));
        __syncthreads();

        for (int p = 0; p < 16; ++p) {
            if (p > 0 && wid >= p) {
                unsigned long long kp = kwsS[p - 1];
                unsigned long long m = ((kp >> lane) & 1ull) ? Msh[wid * KSEL + (p - 1) * 64 + lane] : 0ull;
                if (m) atomicAnd(&kwsS[wid], ~m);
            }
            if (wid == p) {
                __threadfence_block();
                const int row = p * 64 + lane;
                unsigned long long m = (row < KSEL) ? Msh[p * KSEL + row] : 0ull;
                unsigned long long k = kwsS[p];
                unsigned long long processed = 0ull;
                while (true) {
                    unsigned long long sup = __ballot((m & k) != 0ull);
                    unsigned long long rem = k & sup & ~processed;
                    if (!rem) break;
                    int b = __ffsll((long long)rem) - 1;
                    unsigned lo = (unsigned)__builtin_amdgcn_readlane((int)(unsigned)(m & 0xFFFFFFFFull), b);
                    unsigned hi = (unsigned)__builtin_amdgcn_readlane((int)(unsigned)(m >> 32), b);
                    unsigned long long vict = ((unsigned long long)hi << 32) | lo;
                    k &= ~vict;
                    processed = (1ull << b) | ((1ull << b) - 1ull);
                }
                if (lane == 0) kwsS[p] = k;
            }
            __syncthreads();
        }

        if (tid == 0) {
            int pk = 0, pn = 0;
            for (int l = 0; l < 16; ++l) {
                prefK[l] = pk; prefN[l] = pn;
                int limit = KSEL - 64 * l; if (limit > 64) limit = 64;
                int kb = (int)__popcll(kwsS[l]);
                pk += kb; pn += limit - kb;
            }
            totK = pk;
        }
        __syncthreads();

        if (tid < 16) {
            unsigned long long kw = kwsS[tid];
            int limit = KSEL - 64 * tid; if (limit > 64) limit = 64;
            int ck = prefK[tid], cn = totK + prefN[tid];
            for (int b = 0; b < limit; ++b) {
                int jj = tid * 64 + b;
                if ((kw >> b) & 1ull) {
                    order[task * KSEL + ck] = jj;
                    s2v[task * KSEL + ck] = score[task * KSEL + jj];
                    ++ck;
                } else {
                    order[task * KSEL + cn] = jj;
                    s2v[task * KSEL + cn] = NEG_INF_D;
                    ++cn;
                }
            }
        }
    }
    grid.sync();

    // ================= P7: 3-way merge + level assign (blocks 0..7) =================
    if (bid < NIMG) {
        const int img = bid;
        unsigned long long* Mkey = U64;                // 1000 u64
        int* Mid = (int*)(U64 + 1000);                 // 1000 int

        const double* L0 = s2v + (size_t)(img * 3 + 0) * KSEL;
        const double* L1 = s2v + (size_t)(img * 3 + 1) * KSEL;
        const double* L2 = s2v + (size_t)(img * 3 + 2) * KSEL;

        if (tid < KSEL) {
            const int r = tid;
            int lo = 0, hi = r;
            while (lo < hi) {
                int a = (lo + hi) >> 1;
                if (dkey(L0[a]) >= dkey(L1[r - 1 - a])) lo = a + 1; else hi = a;
            }
            int a = lo, b = r - a;
            unsigned long long ka = dkey(L0[a]), kb = dkey(L1[b]);
            if (ka >= kb) { Mkey[r] = ka; Mid[r] = a; }
            else          { Mkey[r] = kb; Mid[r] = 1000 + b; }
        }
        __syncthreads();

        if (tid < KSEL) {
            const int r = tid;
            int lo = 0, hi = r;
            while (lo < hi) {
                int a = (lo + hi) >> 1;
                if (Mkey[a] >= dkey(L2[r - 1 - a])) lo = a + 1; else hi = a;
            }
            int a = lo, b = r - a;
            int e;
            if (a < KSEL && Mkey[a] >= dkey(L2[b])) e = Mid[a];
            else e = 2000 + b;

            int l = e / 1000, rr = e - l * 1000;
            int task = img * 3 + l;
            int pos = order[task * KSEL + rr];
            const double* bo = boxes + (size_t)(task * KSEL + pos) * 4;
            double b0 = bo[0], b1 = bo[1], b2 = bo[2], b3 = bo[3];
            double s = s2v[task * KSEL + rr];

            float* fb = out + ((size_t)img * KSEL + r) * 4;
            fb[0] = (float)b0; fb[1] = (float)b1; fb[2] = (float)b2; fb[3] = (float)b3;
            out[8 * KSEL * 4 + img * KSEL + r] = (float)s;

            double area = (b2 - b0 + 1.0) * (b3 - b1 + 1.0);
            double lv = floor(4.0 + log2(sqrt(area) / 224.0 + 1e-6));
            if (!(lv >= 2.0)) lv = 2.0;
            if (lv > 5.0) lv = 5.0;
            out[8 * KSEL * 5 + img * KSEL + r] = (float)lv;
        }
    }
}

// ---------- launch (1 cooperative node) ----------

extern "C" void kernel_launch(void* const* d_in, const int* in_sizes, int n_in,
                              void* d_out, int out_size, void* d_ws, size_t ws_size,
                              hipStream_t stream) {
    const float* o2 = (const float*)d_in[0];
    const float* o3 = (const float*)d_in[1];
    const float* o4 = (const float*)d_in[2];
    const float* g2 = (const float*)d_in[3];
    const float* g3 = (const float*)d_in[4];
    const float* g4 = (const float*)d_in[5];
    const float* a2 = (const float*)d_in[6];
    const float* a3 = (const float*)d_in[7];
    const float* a4 = (const float*)d_in[8];

    char* ws = (char*)d_ws;
    int*                valid = (int*)(ws + 96000);
    double*             score = (double*)(ws + 192000);
    double*             boxes = (double*)(ws + 384000);
    int*                order = (int*)(ws + 1152000);
    double*             s2    = (double*)(ws + 1248000);
    char*               scr   = ws + 1440000;

    unsigned long long* sorted64 = (unsigned long long*)(ws + 1152000); // overlays order+s2 (dead until P6)
    unsigned*           hist  = (unsigned*)(scr + 0);                   // 393,216 B
    int*                cntB  = (int*)(scr + 393216);                   //   3,072 B
    unsigned long long* cand  = (unsigned long long*)(scr + 396288);    // 1,179,648 B
    unsigned long long* maskT = (unsigned long long*)scr;               // overlays hist/cand (dead after P3)

    float* outp = (float*)d_out;

    void* args[] = {
        (void*)&o2, (void*)&o3, (void*)&o4,
        (void*)&g2, (void*)&g3, (void*)&g4,
        (void*)&a2, (void*)&a3, (void*)&a4,
        (void*)&hist, (void*)&cntB, (void*)&cand,
        (void*)&sorted64,
        (void*)&boxes, (void*)&score, (void*)&valid,
        (void*)&maskT,
        (void*)&order, (void*)&s2,
        (void*)&outp
    };
    hipLaunchCooperativeKernel((void*)k_mega, dim3(NBLK), dim3(1024), args, 0, stream);
}

// Round 16
// 126.612 us; speedup vs baseline: 2.3993x; 2.3993x over previous
//
#include <hip/hip_runtime.h>

#define NTASK 24
#define KSEL 1000
#define NIMG 8
#define NEG_INF_D (-1e30)
#define NSEG 4           // candidate segments per task (one per block)
#define SEGCAP 2048
#define SORTN 2048

// ---------- helpers ----------

static __device__ __forceinline__ unsigned fkey(float x) {
    unsigned u = __float_as_uint(x);
    return u ^ ((u >> 31) ? 0xFFFFFFFFu : 0x80000000u);
}

static __device__ __forceinline__ float fkey_inv(unsigned key) {
    unsigned u = (key >> 31) ? (key ^ 0x80000000u) : ~key;
    return __uint_as_float(u);
}

static __device__ __forceinline__ unsigned long long dkey(double d) {
    unsigned long long u = (unsigned long long)__double_as_longlong(d);
    if (u >> 63) u = ~u; else u |= 0x8000000000000000ull;
    return u;
}

static __device__ __forceinline__ int level_hw(int lvl) {
    return lvl == 0 ? 65536 : (lvl == 1 ? 16384 : 4096);
}

// ---------- phase 1: fused hist+threshold+compact ----------
// Each block builds the FULL task histogram in LDS (redundant across the 4
// blocks of a task -> no cross-block dependency, no global hist, no zeroing),
// computes the threshold, then compacts its own quarter of the data.

__global__ __launch_bounds__(1024) void k_histcompact(
    const float* __restrict__ o2, const float* __restrict__ o3, const float* __restrict__ o4,
    int* __restrict__ cntB, unsigned long long* __restrict__ cand) {

    const int task = blockIdx.x, quarter = blockIdx.y;
    const int img = task / 3, lvl = task % 3;
    const float* obj = lvl == 0 ? o2 : (lvl == 1 ? o3 : o4);
    const int HW = level_hw(lvl);
    const int total = 3 * HW;
    const float* base = obj + (size_t)img * total;
    const int tid = threadIdx.x;

    __shared__ unsigned h[4096];
    __shared__ unsigned part[256];
    __shared__ int sBin;
    __shared__ unsigned long long buf[SEGCAP];
    __shared__ unsigned scnt;

    for (int t = tid; t < 4096; t += 1024) h[t] = 0u;
    if (tid == 0) scnt = 0u;
    __syncthreads();

    // full-task histogram (float4)
    const int total4 = total >> 2;
    const float4* b4 = (const float4*)base;
    for (int t = tid; t < total4; t += 1024) {
        float4 v = b4[t];
        atomicAdd(&h[fkey(v.x) >> 20], 1u);
        atomicAdd(&h[fkey(v.y) >> 20], 1u);
        atomicAdd(&h[fkey(v.z) >> 20], 1u);
        atomicAdd(&h[fkey(v.w) >> 20], 1u);
    }
    __syncthreads();

    // threshold (identical algorithm to the old k_thresh)
    if (tid < 256) {
        unsigned sacc = 0;
        for (int q = 0; q < 16; ++q) sacc += h[tid * 16 + q];
        part[tid] = sacc;
    }
    __syncthreads();
    if (tid == 0) {
        unsigned cum = 0;
        int c = 255;
        for (; c >= 0; --c) {
            if (cum + part[c] >= (unsigned)KSEL) break;
            cum += part[c];
        }
        if (c < 0) c = 0;
        int bin = 0;
        for (int b = c * 16 + 15; b >= c * 16; --b) {
            if (cum + h[b] >= (unsigned)KSEL) { bin = b; break; }
            cum += h[b];
        }
        sBin = bin;
    }
    __syncthreads();
    const unsigned B = (unsigned)sBin;

    // compact own quarter
    const int qper4 = total4 >> 2;
    const int beg4 = quarter * qper4;
    for (int t = beg4 + tid; t < beg4 + qper4; t += 1024) {
        float4 v = b4[t];
        const int e0 = t * 4;
#pragma unroll
        for (int q = 0; q < 4; ++q) {
            float x = q == 0 ? v.x : (q == 1 ? v.y : (q == 2 ? v.z : v.w));
            unsigned key = fkey(x);
            if ((key >> 20) >= B) {
                unsigned s = atomicAdd(&scnt, 1u);
                if (s < (unsigned)SEGCAP) {
                    int el = e0 + q;
                    int a = el / HW, pos = el - a * HW;
                    int i = pos * 3 + a;
                    buf[s] = ((unsigned long long)key << 32) | (unsigned)(~(unsigned)i);
                }
            }
        }
    }
    __syncthreads();
    int n = (int)scnt; if (n > SEGCAP) n = SEGCAP;
    const int seg = task * NSEG + quarter;
    if (tid == 0) cntB[seg] = n;
    unsigned long long* C = cand + (size_t)seg * SEGCAP;
    for (int t = tid; t < n; t += 1024) C[t] = buf[t];
}

// ---------- phase 2: gather + bitonic sort, emit sorted u64 ----------

__global__ __launch_bounds__(1024) void k_sel(const int* __restrict__ cntB,
                                              const unsigned long long* __restrict__ cand,
                                              unsigned long long* __restrict__ sorted64) {
    const int task = blockIdx.x, tid = threadIdx.x;
    const int wid = tid >> 6, lane = tid & 63;
    __shared__ unsigned long long comp[SORTN];
    __shared__ int pref[NSEG + 1];

    if (tid == 0) {
        int p = 0;
        for (int s = 0; s < NSEG; ++s) { pref[s] = p; p += cntB[task * NSEG + s]; }
        pref[NSEG] = p;
    }
    for (int t = tid; t < SORTN; t += 1024) comp[t] = 0ull;
    __syncthreads();

    for (int s = wid; s < NSEG; s += 16) {
        const int b = pref[s], n = pref[s + 1] - b;
        const unsigned long long* C = cand + (size_t)(task * NSEG + s) * SEGCAP;
        for (int k = lane; k < n; k += 64)
            if (b + k < SORTN) comp[b + k] = C[k];
    }
    __syncthreads();

    for (unsigned k = 2; k <= SORTN; k <<= 1) {
        for (unsigned j = k >> 1; j > 0; j >>= 1) {
            for (unsigned i = tid; i < SORTN; i += 1024) {
                unsigned ixj = i ^ j;
                if (ixj > i) {
                    unsigned long long A = comp[i], Bv = comp[ixj];
                    bool desc = ((i & k) == 0);
                    if ((A < Bv) == desc) { comp[i] = Bv; comp[ixj] = A; }
                }
            }
            __syncthreads();
        }
    }

    for (int t = tid; t < KSEL; t += 1024) sorted64[task * KSEL + t] = comp[t];
}

// ---------- phase 3: decode (192 blocks for gather latency hiding) ----------

__global__ __launch_bounds__(128) void k_decode(
    const unsigned long long* __restrict__ sorted64,
    const float* __restrict__ g2, const float* __restrict__ g3, const float* __restrict__ g4,
    const float* __restrict__ a2, const float* __restrict__ a3, const float* __restrict__ a4,
    double* __restrict__ boxes, double* __restrict__ score, int* __restrict__ valid) {

    const int task = blockIdx.x, img = task / 3, lvl = task % 3;
    const int r = blockIdx.y * 125 + threadIdx.x;
    if (threadIdx.x >= 125) return;

    const float* brg = lvl == 0 ? g2 : (lvl == 1 ? g3 : g4);
    const float* anc = lvl == 0 ? a2 : (lvl == 1 ? a3 : a4);
    const int HW = level_hw(lvl);
    const int N = HW * 3;
    const double XC = 4.135166556742356;   // log(1000/16)

    unsigned long long e = sorted64[task * KSEL + r];
    unsigned key = (unsigned)(e >> 32);
    int i = (int)(~(unsigned)(e & 0xFFFFFFFFull));
    int a = i % 3, pos = i / 3;

    double x = (double)fkey_inv(key);
    double s = 1.0 / (1.0 + exp(-x));

    const float* bb = brg + (size_t)img * 12 * HW + (size_t)(a * 4) * HW + pos;
    double dx = (double)bb[0];
    double dy = (double)bb[(size_t)HW];
    double dw = (double)bb[(size_t)2 * HW];
    double dh = (double)bb[(size_t)3 * HW];

    const float* an = anc + ((size_t)img * N + (size_t)i) * 4;
    double ax1 = an[0], ay1 = an[1], ax2 = an[2], ay2 = an[3];

    double w = ax2 - ax1 + 1.0, h = ay2 - ay1 + 1.0;
    double cx = ax1 + 0.5 * w, cy = ay1 + 0.5 * h;
    if (dw > XC) dw = XC;
    if (dh > XC) dh = XC;
    double pcx = dx * w + cx, pcy = dy * h + cy;
    double pw = exp(dw) * w, ph = exp(dh) * h;
    double x1 = pcx - 0.5 * pw, y1 = pcy - 0.5 * ph;
    double x2 = pcx + 0.5 * pw - 1.0, y2 = pcy + 0.5 * ph - 1.0;
    x1 = fmin(fmax(x1, 0.0), 1023.0);
    y1 = fmin(fmax(y1, 0.0), 1023.0);
    x2 = fmin(fmax(x2, 0.0), 1023.0);
    y2 = fmin(fmax(y2, 0.0), 1023.0);
    double ws_ = x2 - x1 + 1.0, hs_ = y2 - y1 + 1.0;
    double xc = x1 + ws_ / 2.0, yc = y1 + hs_ / 2.0;
    int v = (ws_ >= 0.0) && (hs_ >= 0.0) && (xc < 1024.0) && (yc < 1024.0);

    double* bo = boxes + (size_t)(task * KSEL + r) * 4;
    bo[0] = x1; bo[1] = y1; bo[2] = x2; bo[3] = y2;
    score[task * KSEL + r] = s;
    valid[task * KSEL + r] = v;
}

// ---------- phase 4: suppression mask, transposed maskT[task][J][i], one wave per tile ----------

__global__ __launch_bounds__(512) void k_mask(const double* __restrict__ boxes,
                                              unsigned long long* __restrict__ maskT) {
    const int task = blockIdx.x;
    const int wid = threadIdx.x >> 6, lane = threadIdx.x & 63;
    const int t = blockIdx.y * 8 + wid;          // 17*8 = 136 triangular tiles
    if (t >= 136) return;
    int I = 0, rem = t;
    while (rem >= 16 - I) { rem -= 16 - I; ++I; }
    const int J = I + rem;

    const double* B = boxes + (size_t)task * KSEL * 4;
    const int j = J * 64 + lane;
    const int jc = j < KSEL ? j : KSEL - 1;
    double jx1 = B[jc * 4 + 0], jy1 = B[jc * 4 + 1];
    double jx2 = B[jc * 4 + 2], jy2 = B[jc * 4 + 3];
    double aj = (jx2 - jx1 + 1.0) * (jy2 - jy1 + 1.0);

    unsigned long long* MT = maskT + (size_t)task * 16000 + (size_t)J * KSEL;
    int iend = I * 64 + 64; if (iend > KSEL) iend = KSEL;
    for (int i = I * 64; i < iend; ++i) {
        double ix1 = B[i * 4 + 0], iy1 = B[i * 4 + 1];
        double ix2 = B[i * 4 + 2], iy2 = B[i * 4 + 3];
        double ai = (ix2 - ix1 + 1.0) * (iy2 - iy1 + 1.0);
        double xx1 = fmax(ix1, jx1), yy1 = fmax(iy1, jy1);
        double xx2 = fmin(ix2, jx2), yy2 = fmin(iy2, jy2);
        double iw = xx2 - xx1 + 1.0; iw = iw > 0.0 ? iw : 0.0;
        double ih = yy2 - yy1 + 1.0; ih = ih > 0.0 ? ih : 0.0;
        double inter = iw * ih;
        double iou = inter / (ai + aj - inter);
        bool sup = (j > i) && (j < KSEL) && (iou > 0.7);
        unsigned long long m = __ballot(sup);
        if (lane == 0) MT[i] = m;
    }
}

// ---------- phase 5: greedy NMS (LDS mask, ballot-skip resolve, sparse atomicAnd) ----------

__global__ __launch_bounds__(1024) void k_nms(const unsigned long long* __restrict__ maskT,
                                              const int* __restrict__ valid,
                                              const double* __restrict__ score,
                                              int* __restrict__ order, double* __restrict__ s2) {
    const int task = blockIdx.x;
    const int tid = threadIdx.x;
    const int wid = tid >> 6, lane = tid & 63;

    __shared__ unsigned long long Msh[16000];   // 128 KB: Msh[J*1000 + i]
    __shared__ unsigned long long kws[16];
    __shared__ int prefK[16], prefN[16], totKsh;

    {
        const ulonglong2* MG = (const ulonglong2*)(maskT + (size_t)task * 16000);
        ulonglong2* ML = (ulonglong2*)Msh;
        for (int t = tid; t < 8000; t += 1024) ML[t] = MG[t];
    }
    if (tid < 16) kws[tid] = 0ull;
    __syncthreads();
    if (tid < KSEL && valid[task * KSEL + tid])
        atomicOr(&kws[tid >> 6], 1ull << (tid & 63));
    __syncthreads();

    for (int p = 0; p < 16; ++p) {
        if (p > 0 && wid >= p) {
            unsigned long long kp = kws[p - 1];
            unsigned long long m = ((kp >> lane) & 1ull) ? Msh[wid * KSEL + (p - 1) * 64 + lane] : 0ull;
            if (m) atomicAnd(&kws[wid], ~m);
        }
        if (wid == p) {
            __threadfence_block();
            const int row = p * 64 + lane;
            unsigned long long m = (row < KSEL) ? Msh[p * KSEL + row] : 0ull;
            unsigned long long k = kws[p];
            unsigned long long processed = 0ull;
            while (true) {
                unsigned long long sup = __ballot((m & k) != 0ull);
                unsigned long long rem = k & sup & ~processed;
                if (!rem) break;
                int b = __ffsll((long long)rem) - 1;
                unsigned lo = (unsigned)__builtin_amdgcn_readlane((int)(unsigned)(m & 0xFFFFFFFFull), b);
                unsigned hi = (unsigned)__builtin_amdgcn_readlane((int)(unsigned)(m >> 32), b);
                unsigned long long vict = ((unsigned long long)hi << 32) | lo;
                k &= ~vict;
                processed = (1ull << b) | ((1ull << b) - 1ull);
            }
            if (lane == 0) kws[p] = k;
        }
        __syncthreads();
    }

    if (tid == 0) {
        int pk = 0, pn = 0;
        for (int l = 0; l < 16; ++l) {
            prefK[l] = pk; prefN[l] = pn;
            int limit = KSEL - 64 * l; if (limit > 64) limit = 64;
            int kb = (int)__popcll(kws[l]);
            pk += kb; pn += limit - kb;
        }
        totKsh = pk;
    }
    __syncthreads();

    if (tid < 16) {
        unsigned long long kw = kws[tid];
        int limit = KSEL - 64 * tid; if (limit > 64) limit = 64;
        int ck = prefK[tid], cn = totKsh + prefN[tid];
        for (int b = 0; b < limit; ++b) {
            int jj = tid * 64 + b;
            if ((kw >> b) & 1ull) {
                order[task * KSEL + ck] = jj;
                s2[task * KSEL + ck] = score[task * KSEL + jj];
                ++ck;
            } else {
                order[task * KSEL + cn] = jj;
                s2[task * KSEL + cn] = NEG_INF_D;
                ++cn;
            }
        }
    }
}

// ---------- phase 6: per-image 3-way sorted merge (merge-path), level assign ----------

__global__ __launch_bounds__(1024) void k_final(const double* __restrict__ boxes,
                                                const double* __restrict__ s2,
                                                const int* __restrict__ order,
                                                float* __restrict__ out) {
    const int img = blockIdx.x;
    const int tid = threadIdx.x;
    __shared__ unsigned long long Mkey[KSEL];
    __shared__ int Mid[KSEL];

    const double* L0 = s2 + (size_t)(img * 3 + 0) * KSEL;
    const double* L1 = s2 + (size_t)(img * 3 + 1) * KSEL;
    const double* L2 = s2 + (size_t)(img * 3 + 2) * KSEL;

    if (tid < KSEL) {
        const int r = tid;
        int lo = 0, hi = r;
        while (lo < hi) {
            int a = (lo + hi) >> 1;
            if (dkey(L0[a]) >= dkey(L1[r - 1 - a])) lo = a + 1; else hi = a;
        }
        int a = lo, b = r - a;
        unsigned long long ka = dkey(L0[a]), kb = dkey(L1[b]);
        if (ka >= kb) { Mkey[r] = ka; Mid[r] = a; }
        else          { Mkey[r] = kb; Mid[r] = 1000 + b; }
    }
    __syncthreads();

    if (tid < KSEL) {
        const int r = tid;
        int lo = 0, hi = r;
        while (lo < hi) {
            int a = (lo + hi) >> 1;
            if (Mkey[a] >= dkey(L2[r - 1 - a])) lo = a + 1; else hi = a;
        }
        int a = lo, b = r - a;
        int e;
        if (a < KSEL && Mkey[a] >= dkey(L2[b])) e = Mid[a];
        else e = 2000 + b;

        int l = e / 1000, rr = e - l * 1000;
        int task = img * 3 + l;
        int pos = order[task * KSEL + rr];
        const double* bo = boxes + (size_t)(task * KSEL + pos) * 4;
        double b0 = bo[0], b1 = bo[1], b2 = bo[2], b3 = bo[3];
        double s = s2[task * KSEL + rr];

        float* fb = out + ((size_t)img * KSEL + r) * 4;
        fb[0] = (float)b0; fb[1] = (float)b1; fb[2] = (float)b2; fb[3] = (float)b3;
        out[8 * KSEL * 4 + img * KSEL + r] = (float)s;

        double area = (b2 - b0 + 1.0) * (b3 - b1 + 1.0);
        double lv = floor(4.0 + log2(sqrt(area) / 224.0 + 1e-6));
        if (!(lv >= 2.0)) lv = 2.0;
        if (lv > 5.0) lv = 5.0;
        out[8 * KSEL * 5 + img * KSEL + r] = (float)lv;
    }
}

// ---------- launch (6 nodes) ----------

extern "C" void kernel_launch(void* const* d_in, const int* in_sizes, int n_in,
                              void* d_out, int out_size, void* d_ws, size_t ws_size,
                              hipStream_t stream) {
    const float* o2 = (const float*)d_in[0];
    const float* o3 = (const float*)d_in[1];
    const float* o4 = (const float*)d_in[2];
    const float* g2 = (const float*)d_in[3];
    const float* g3 = (const float*)d_in[4];
    const float* g4 = (const float*)d_in[5];
    const float* a2 = (const float*)d_in[6];
    const float* a3 = (const float*)d_in[7];
    const float* a4 = (const float*)d_in[8];

    char* ws = (char*)d_ws;
    int*                valid = (int*)(ws + 96000);      //  96,000 B
    double*             score = (double*)(ws + 192000);  // 192,000 B
    double*             boxes = (double*)(ws + 384000);  // 768,000 B
    int*                order = (int*)(ws + 1152000);    //  96,000 B
    double*             s2    = (double*)(ws + 1248000); // 192,000 B
    char*               scr   = ws + 1440000;            // 3,072,000 B shared region

    // sorted64 overlays order+s2[0:192000): written by k_sel, last read by
    // k_decode; order/s2 only written by k_nms. Stream-serial -> safe.
    unsigned long long* sorted64 = (unsigned long long*)(ws + 1152000); // 192,000 B

    // scr overlay: cntB/cand live until k_sel; maskT written by k_mask after.
    int*                cntB  = (int*)(scr + 0);                        //     384 B
    unsigned long long* cand  = (unsigned long long*)(scr + 1024);      // 1,572,864 B
    unsigned long long* maskT = (unsigned long long*)scr;               // 3,072,000 B

    k_histcompact<<<dim3(NTASK, NSEG), 1024, 0, stream>>>(o2, o3, o4, cntB, cand);
    k_sel<<<NTASK, 1024, 0, stream>>>(cntB, cand, sorted64);
    k_decode<<<dim3(NTASK, 8), 128, 0, stream>>>(sorted64, g2, g3, g4, a2, a3, a4,
                                                 boxes, score, valid);
    k_mask<<<dim3(NTASK, 17), 512, 0, stream>>>(boxes, maskT);
    k_nms<<<NTASK, 1024, 0, stream>>>(maskT, valid, score, order, s2);
    k_final<<<NIMG, 1024, 0, stream>>>(boxes, s2, order, (float*)d_out);
}

// Round 17
// 114.616 us; speedup vs baseline: 2.6504x; 1.1047x over previous
//
#include <hip/hip_runtime.h>

#define NTASK 24
#define KSEL 1000
#define NIMG 8
#define NEG_INF_D (-1e30)
#define SEG 192          // per-block candidate segment
#define SORTN 2048

// ---------- helpers ----------

static __device__ __forceinline__ unsigned fkey(float x) {
    unsigned u = __float_as_uint(x);
    return u ^ ((u >> 31) ? 0xFFFFFFFFu : 0x80000000u);
}

static __device__ __forceinline__ float fkey_inv(unsigned key) {
    unsigned u = (key >> 31) ? (key ^ 0x80000000u) : ~key;
    return __uint_as_float(u);
}

static __device__ __forceinline__ unsigned long long dkey(double d) {
    unsigned long long u = (unsigned long long)__double_as_longlong(d);
    if (u >> 63) u = ~u; else u |= 0x8000000000000000ull;
    return u;
}

static __device__ __forceinline__ int level_hw(int lvl) {
    return lvl == 0 ? 65536 : (lvl == 1 ? 16384 : 4096);
}

// ---------- phase 0: zero hist ----------

__global__ __launch_bounds__(256) void k_zero(uint4* __restrict__ p, int n16) {
    const int t = blockIdx.x * 256 + threadIdx.x;
    if (t < n16) p[t] = make_uint4(0u, 0u, 0u, 0u);
}

// ---------- phase 1: per-task 4096-bin histogram (2x privatized LDS, float4) ----------

__global__ __launch_bounds__(256) void k_hist(const float* __restrict__ o2,
                                              const float* __restrict__ o3,
                                              const float* __restrict__ o4,
                                              unsigned* __restrict__ hist) {
    const int task = blockIdx.x, img = task / 3, lvl = task % 3;
    const float* obj = lvl == 0 ? o2 : (lvl == 1 ? o3 : o4);
    const int HW = level_hw(lvl);
    const int total = 3 * HW;
    const float* base = obj + (size_t)img * total;
    const int tid = threadIdx.x;

    __shared__ unsigned h0[4096];
    __shared__ unsigned h1[4096];
    for (int t = tid; t < 4096; t += 256) { h0[t] = 0u; h1[t] = 0u; }
    __syncthreads();

    // waves 0-1 -> h0, waves 2-3 -> h1: halves same-bin atomic serialization
    unsigned* h = (tid < 128) ? h0 : h1;

    const int per4 = (total / 32) >> 2;
    const int beg4 = blockIdx.y * per4;
    const float4* base4 = (const float4*)base;
    for (int t = beg4 + tid; t < beg4 + per4; t += 256) {
        float4 v = base4[t];
        atomicAdd(&h[fkey(v.x) >> 20], 1u);
        atomicAdd(&h[fkey(v.y) >> 20], 1u);
        atomicAdd(&h[fkey(v.z) >> 20], 1u);
        atomicAdd(&h[fkey(v.w) >> 20], 1u);
    }
    __syncthreads();

    unsigned* H = hist + task * 4096;
    for (int t = tid; t < 4096; t += 256) {
        unsigned c = h0[t] + h1[t];
        if (c) atomicAdd(&H[t], c);
    }
}

// ---------- phase 2: compact candidates; threshold computed inline per block ----------

__global__ __launch_bounds__(256) void k_compact(const float* __restrict__ o2,
                                                 const float* __restrict__ o3,
                                                 const float* __restrict__ o4,
                                                 const unsigned* __restrict__ hist,
                                                 int* __restrict__ cntB,
                                                 unsigned long long* __restrict__ cand) {
    const int task = blockIdx.x, img = task / 3, lvl = task % 3;
    const float* obj = lvl == 0 ? o2 : (lvl == 1 ? o3 : o4);
    const int HW = level_hw(lvl);
    const int total = 3 * HW;
    const float* base = obj + (size_t)img * total;
    const int tid = threadIdx.x;

    __shared__ unsigned h[4096];
    __shared__ unsigned part[256];
    __shared__ int sBin;
    __shared__ unsigned long long buf[256];
    __shared__ unsigned scnt;

    // inline threshold: identical algorithm to the old k_thresh
    const unsigned* H = hist + task * 4096;
    for (int t = tid; t < 4096; t += 256) h[t] = H[t];
    if (tid == 0) scnt = 0u;
    __syncthreads();
    unsigned sacc = 0;
    for (int q = 0; q < 16; ++q) sacc += h[tid * 16 + q];
    part[tid] = sacc;
    __syncthreads();
    if (tid == 0) {
        unsigned cum = 0;
        int c = 255;
        for (; c >= 0; --c) {
            if (cum + part[c] >= (unsigned)KSEL) break;
            cum += part[c];
        }
        if (c < 0) c = 0;
        int bin = 0;
        for (int b = c * 16 + 15; b >= c * 16; --b) {
            if (cum + h[b] >= (unsigned)KSEL) { bin = b; break; }
            cum += h[b];
        }
        sBin = bin;
    }
    __syncthreads();
    const unsigned B = (unsigned)sBin;

    const int per4 = (total / 32) >> 2;
    const int beg4 = blockIdx.y * per4;
    const float4* base4 = (const float4*)base;
    for (int t = beg4 + tid; t < beg4 + per4; t += 256) {
        float4 v = base4[t];
        const int e0 = t * 4;
#pragma unroll
        for (int q = 0; q < 4; ++q) {
            float x = q == 0 ? v.x : (q == 1 ? v.y : (q == 2 ? v.z : v.w));
            unsigned key = fkey(x);
            if ((key >> 20) >= B) {
                unsigned s = atomicAdd(&scnt, 1u);
                if (s < 256u) {
                    int el = e0 + q;
                    int a = el / HW, pos = el - a * HW;
                    int i = pos * 3 + a;
                    buf[s] = ((unsigned long long)key << 32) | (unsigned)(~(unsigned)i);
                }
            }
        }
    }
    __syncthreads();
    int n = (int)scnt; if (n > SEG) n = SEG;
    const int seg = task * 32 + blockIdx.y;
    if (tid == 0) cntB[seg] = n;
    unsigned long long* C = cand + (size_t)seg * SEG;
    for (int t = tid; t < n; t += 256) C[t] = buf[t];
}

// ---------- phase 3: gather (per-wave parallel) + bitonic sort, emit sorted u64 ----------

__global__ __launch_bounds__(1024) void k_sel(const int* __restrict__ cntB,
                                              const unsigned long long* __restrict__ cand,
                                              unsigned long long* __restrict__ sorted64) {
    const int task = blockIdx.x, tid = threadIdx.x;
    const int wid = tid >> 6, lane = tid & 63;
    __shared__ unsigned long long comp[SORTN];
    __shared__ int pref[33];

    if (tid == 0) {
        int p = 0;
        for (int s = 0; s < 32; ++s) { pref[s] = p; p += cntB[task * 32 + s]; }
        pref[32] = p;
    }
    for (int t = tid; t < SORTN; t += 1024) comp[t] = 0ull;
    __syncthreads();

    for (int s = wid; s < 32; s += 16) {
        const int b = pref[s], n = pref[s + 1] - b;
        const unsigned long long* C = cand + (size_t)(task * 32 + s) * SEG;
        for (int k = lane; k < n; k += 64)
            if (b + k < SORTN) comp[b + k] = C[k];
    }
    __syncthreads();

    for (unsigned k = 2; k <= SORTN; k <<= 1) {
        for (unsigned j = k >> 1; j > 0; j >>= 1) {
            for (unsigned i = tid; i < SORTN; i += 1024) {
                unsigned ixj = i ^ j;
                if (ixj > i) {
                    unsigned long long A = comp[i], Bv = comp[ixj];
                    bool desc = ((i & k) == 0);
                    if ((A < Bv) == desc) { comp[i] = Bv; comp[ixj] = A; }
                }
            }
            __syncthreads();
        }
    }

    for (int t = tid; t < KSEL; t += 1024) sorted64[task * KSEL + t] = comp[t];
}

// ---------- phase 4: decode (192 blocks for gather latency hiding) ----------

__global__ __launch_bounds__(128) void k_decode(
    const unsigned long long* __restrict__ sorted64,
    const float* __restrict__ g2, const float* __restrict__ g3, const float* __restrict__ g4,
    const float* __restrict__ a2, const float* __restrict__ a3, const float* __restrict__ a4,
    double* __restrict__ boxes, double* __restrict__ score, int* __restrict__ valid) {

    const int task = blockIdx.x, img = task / 3, lvl = task % 3;
    const int r = blockIdx.y * 125 + threadIdx.x;
    if (threadIdx.x >= 125) return;

    const float* brg = lvl == 0 ? g2 : (lvl == 1 ? g3 : g4);
    const float* anc = lvl == 0 ? a2 : (lvl == 1 ? a3 : a4);
    const int HW = level_hw(lvl);
    const int N = HW * 3;
    const double XC = 4.135166556742356;   // log(1000/16)

    unsigned long long e = sorted64[task * KSEL + r];
    unsigned key = (unsigned)(e >> 32);
    int i = (int)(~(unsigned)(e & 0xFFFFFFFFull));
    int a = i % 3, pos = i / 3;

    double x = (double)fkey_inv(key);
    double s = 1.0 / (1.0 + exp(-x));

    const float* bb = brg + (size_t)img * 12 * HW + (size_t)(a * 4) * HW + pos;
    double dx = (double)bb[0];
    double dy = (double)bb[(size_t)HW];
    double dw = (double)bb[(size_t)2 * HW];
    double dh = (double)bb[(size_t)3 * HW];

    const float* an = anc + ((size_t)img * N + (size_t)i) * 4;
    double ax1 = an[0], ay1 = an[1], ax2 = an[2], ay2 = an[3];

    double w = ax2 - ax1 + 1.0, h = ay2 - ay1 + 1.0;
    double cx = ax1 + 0.5 * w, cy = ay1 + 0.5 * h;
    if (dw > XC) dw = XC;
    if (dh > XC) dh = XC;
    double pcx = dx * w + cx, pcy = dy * h + cy;
    double pw = exp(dw) * w, ph = exp(dh) * h;
    double x1 = pcx - 0.5 * pw, y1 = pcy - 0.5 * ph;
    double x2 = pcx + 0.5 * pw - 1.0, y2 = pcy + 0.5 * ph - 1.0;
    x1 = fmin(fmax(x1, 0.0), 1023.0);
    y1 = fmin(fmax(y1, 0.0), 1023.0);
    x2 = fmin(fmax(x2, 0.0), 1023.0);
    y2 = fmin(fmax(y2, 0.0), 1023.0);
    double ws_ = x2 - x1 + 1.0, hs_ = y2 - y1 + 1.0;
    double xc = x1 + ws_ / 2.0, yc = y1 + hs_ / 2.0;
    int v = (ws_ >= 0.0) && (hs_ >= 0.0) && (xc < 1024.0) && (yc < 1024.0);

    double* bo = boxes + (size_t)(task * KSEL + r) * 4;
    bo[0] = x1; bo[1] = y1; bo[2] = x2; bo[3] = y2;
    score[task * KSEL + r] = s;
    valid[task * KSEL + r] = v;
}

// ---------- phase 5: suppression mask, transposed maskT[task][J][i], one wave per tile ----------

__global__ __launch_bounds__(512) void k_mask(const double* __restrict__ boxes,
                                              unsigned long long* __restrict__ maskT) {
    const int task = blockIdx.x;
    const int wid = threadIdx.x >> 6, lane = threadIdx.x & 63;
    const int t = blockIdx.y * 8 + wid;          // 17*8 = 136 triangular tiles
    if (t >= 136) return;
    int I = 0, rem = t;
    while (rem >= 16 - I) { rem -= 16 - I; ++I; }
    const int J = I + rem;

    const double* B = boxes + (size_t)task * KSEL * 4;
    const int j = J * 64 + lane;
    const int jc = j < KSEL ? j : KSEL - 1;
    double jx1 = B[jc * 4 + 0], jy1 = B[jc * 4 + 1];
    double jx2 = B[jc * 4 + 2], jy2 = B[jc * 4 + 3];
    double aj = (jx2 - jx1 + 1.0) * (jy2 - jy1 + 1.0);

    unsigned long long* MT = maskT + (size_t)task * 16000 + (size_t)J * KSEL;
    int iend = I * 64 + 64; if (iend > KSEL) iend = KSEL;
    for (int i = I * 64; i < iend; ++i) {
        double ix1 = B[i * 4 + 0], iy1 = B[i * 4 + 1];
        double ix2 = B[i * 4 + 2], iy2 = B[i * 4 + 3];
        double ai = (ix2 - ix1 + 1.0) * (iy2 - iy1 + 1.0);
        double xx1 = fmax(ix1, jx1), yy1 = fmax(iy1, jy1);
        double xx2 = fmin(ix2, jx2), yy2 = fmin(iy2, jy2);
        double iw = xx2 - xx1 + 1.0; iw = iw > 0.0 ? iw : 0.0;
        double ih = yy2 - yy1 + 1.0; ih = ih > 0.0 ? ih : 0.0;
        double inter = iw * ih;
        double iou = inter / (ai + aj - inter);
        bool sup = (j > i) && (j < KSEL) && (iou > 0.7);
        unsigned long long m = __ballot(sup);
        if (lane == 0) MT[i] = m;
    }
}

// ---------- phase 6: greedy NMS (LDS mask, ballot-skip resolve, sparse atomicAnd) ----------

__global__ __launch_bounds__(1024) void k_nms(const unsigned long long* __restrict__ maskT,
                                              const int* __restrict__ valid,
                                              const double* __restrict__ score,
                                              int* __restrict__ order, double* __restrict__ s2) {
    const int task = blockIdx.x;
    const int tid = threadIdx.x;
    const int wid = tid >> 6, lane = tid & 63;

    __shared__ unsigned long long Msh[16000];   // 128 KB: Msh[J*1000 + i]
    __shared__ unsigned long long kws[16];
    __shared__ int prefK[16], prefN[16], totKsh;

    {
        const ulonglong2* MG = (const ulonglong2*)(maskT + (size_t)task * 16000);
        ulonglong2* ML = (ulonglong2*)Msh;
        for (int t = tid; t < 8000; t += 1024) ML[t] = MG[t];
    }
    if (tid < 16) kws[tid] = 0ull;
    __syncthreads();
    if (tid < KSEL && valid[task * KSEL + tid])
        atomicOr(&kws[tid >> 6], 1ull << (tid & 63));
    __syncthreads();

    for (int p = 0; p < 16; ++p) {
        if (p > 0 && wid >= p) {
            unsigned long long kp = kws[p - 1];
            unsigned long long m = ((kp >> lane) & 1ull) ? Msh[wid * KSEL + (p - 1) * 64 + lane] : 0ull;
            if (m) atomicAnd(&kws[wid], ~m);
        }
        if (wid == p) {
            __threadfence_block();
            const int row = p * 64 + lane;
            unsigned long long m = (row < KSEL) ? Msh[p * KSEL + row] : 0ull;
            unsigned long long k = kws[p];
            unsigned long long processed = 0ull;
            while (true) {
                unsigned long long sup = __ballot((m & k) != 0ull);
                unsigned long long rem = k & sup & ~processed;
                if (!rem) break;
                int b = __ffsll((long long)rem) - 1;
                unsigned lo = (unsigned)__builtin_amdgcn_readlane((int)(unsigned)(m & 0xFFFFFFFFull), b);
                unsigned hi = (unsigned)__builtin_amdgcn_readlane((int)(unsigned)(m >> 32), b);
                unsigned long long vict = ((unsigned long long)hi << 32) | lo;
                k &= ~vict;
                processed = (1ull << b) | ((1ull << b) - 1ull);
            }
            if (lane == 0) kws[p] = k;
        }
        __syncthreads();
    }

    if (tid == 0) {
        int pk = 0, pn = 0;
        for (int l = 0; l < 16; ++l) {
            prefK[l] = pk; prefN[l] = pn;
            int limit = KSEL - 64 * l; if (limit > 64) limit = 64;
            int kb = (int)__popcll(kws[l]);
            pk += kb; pn += limit - kb;
        }
        totKsh = pk;
    }
    __syncthreads();

    if (tid < 16) {
        unsigned long long kw = kws[tid];
        int limit = KSEL - 64 * tid; if (limit > 64) limit = 64;
        int ck = prefK[tid], cn = totKsh + prefN[tid];
        for (int b = 0; b < limit; ++b) {
            int jj = tid * 64 + b;
            if ((kw >> b) & 1ull) {
                order[task * KSEL + ck] = jj;
                s2[task * KSEL + ck] = score[task * KSEL + jj];
                ++ck;
            } else {
                order[task * KSEL + cn] = jj;
                s2[task * KSEL + cn] = NEG_INF_D;
                ++cn;
            }
        }
    }
}

// ---------- phase 7: per-image 3-way sorted merge (merge-path), level assign ----------

__global__ __launch_bounds__(1024) void k_final(const double* __restrict__ boxes,
                                                const double* __restrict__ s2,
                                                const int* __restrict__ order,
                                                float* __restrict__ out) {
    const int img = blockIdx.x;
    const int tid = threadIdx.x;
    __shared__ unsigned long long Mkey[KSEL];
    __shared__ int Mid[KSEL];

    const double* L0 = s2 + (size_t)(img * 3 + 0) * KSEL;
    const double* L1 = s2 + (size_t)(img * 3 + 1) * KSEL;
    const double* L2 = s2 + (size_t)(img * 3 + 2) * KSEL;

    if (tid < KSEL) {
        const int r = tid;
        int lo = 0, hi = r;
        while (lo < hi) {
            int a = (lo + hi) >> 1;
            if (dkey(L0[a]) >= dkey(L1[r - 1 - a])) lo = a + 1; else hi = a;
        }
        int a = lo, b = r - a;
        unsigned long long ka = dkey(L0[a]), kb = dkey(L1[b]);
        if (ka >= kb) { Mkey[r] = ka; Mid[r] = a; }
        else          { Mkey[r] = kb; Mid[r] = 1000 + b; }
    }
    __syncthreads();

    if (tid < KSEL) {
        const int r = tid;
        int lo = 0, hi = r;
        while (lo < hi) {
            int a = (lo + hi) >> 1;
            if (Mkey[a] >= dkey(L2[r - 1 - a])) lo = a + 1; else hi = a;
        }
        int a = lo, b = r - a;
        int e;
        if (a < KSEL && Mkey[a] >= dkey(L2[b])) e = Mid[a];
        else e = 2000 + b;

        int l = e / 1000, rr = e - l * 1000;
        int task = img * 3 + l;
        int pos = order[task * KSEL + rr];
        const double* bo = boxes + (size_t)(task * KSEL + pos) * 4;
        double b0 = bo[0], b1 = bo[1], b2 = bo[2], b3 = bo[3];
        double s = s2[task * KSEL + rr];

        float* fb = out + ((size_t)img * KSEL + r) * 4;
        fb[0] = (float)b0; fb[1] = (float)b1; fb[2] = (float)b2; fb[3] = (float)b3;
        out[8 * KSEL * 4 + img * KSEL + r] = (float)s;

        double area = (b2 - b0 + 1.0) * (b3 - b1 + 1.0);
        double lv = floor(4.0 + log2(sqrt(area) / 224.0 + 1e-6));
        if (!(lv >= 2.0)) lv = 2.0;
        if (lv > 5.0) lv = 5.0;
        out[8 * KSEL * 5 + img * KSEL + r] = (float)lv;
    }
}

// ---------- launch (8 nodes) ----------

extern "C" void kernel_launch(void* const* d_in, const int* in_sizes, int n_in,
                              void* d_out, int out_size, void* d_ws, size_t ws_size,
                              hipStream_t stream) {
    const float* o2 = (const float*)d_in[0];
    const float* o3 = (const float*)d_in[1];
    const float* o4 = (const float*)d_in[2];
    const float* g2 = (const float*)d_in[3];
    const float* g3 = (const float*)d_in[4];
    const float* g4 = (const float*)d_in[5];
    const float* a2 = (const float*)d_in[6];
    const float* a3 = (const float*)d_in[7];
    const float* a4 = (const float*)d_in[8];

    char* ws = (char*)d_ws;
    int*                valid = (int*)(ws + 96000);      //  96,000 B
    double*             score = (double*)(ws + 192000);  // 192,000 B
    double*             boxes = (double*)(ws + 384000);  // 768,000 B
    int*                order = (int*)(ws + 1152000);    //  96,000 B
    double*             s2    = (double*)(ws + 1248000); // 192,000 B
    char*               scr   = ws + 1440000;            // 3,072,000 B shared region

    // sorted64 overlays order+s2[0:192000): written by k_sel, last read by
    // k_decode; order/s2 only written by k_nms. Stream-serial -> safe.
    unsigned long long* sorted64 = (unsigned long long*)(ws + 1152000); // 192,000 B

    // scr overlay: hist/cntB/cand live until k_sel; maskT written by k_mask after.
    unsigned*           hist  = (unsigned*)(scr + 0);                   // 393,216 B
    int*                cntB  = (int*)(scr + 393216);                   //   3,072 B
    unsigned long long* cand  = (unsigned long long*)(scr + 396288);    // 1,179,648 B
    unsigned long long* maskT = (unsigned long long*)scr;               // 3,072,000 B

    // zero hist (393,216 B = 24,576 uint4)
    k_zero<<<96, 256, 0, stream>>>((uint4*)scr, 24576);

    k_hist<<<dim3(NTASK, 32), 256, 0, stream>>>(o2, o3, o4, hist);
    k_compact<<<dim3(NTASK, 32), 256, 0, stream>>>(o2, o3, o4, hist, cntB, cand);
    k_sel<<<NTASK, 1024, 0, stream>>>(cntB, cand, sorted64);
    k_decode<<<dim3(NTASK, 8), 128, 0, stream>>>(sorted64, g2, g3, g4, a2, a3, a4,
                                                 boxes, score, valid);
    k_mask<<<dim3(NTASK, 17), 512, 0, stream>>>(boxes, maskT);
    k_nms<<<NTASK, 1024, 0, stream>>>(maskT, valid, score, order, s2);
    k_final<<<NIMG, 1024, 0, stream>>>(boxes, s2, order, (float*)d_out);
}